// Round 6
// baseline (2944.651 us; speedup 1.0000x reference)
//
#include <hip/hip_runtime.h>

#define N_NODES 100000
#define N_EDGES 3200000
#define F 128
#define GEMM_BLOCKS 782      // ceil(100000 / 128 nodes per gemm block)
#define SPLIT_BLOCKS 391     // ceil(3.2M / 8192)
#define SPLIT_T 8192
#define NBUCK 782            // buckets of 128 rows: ceil(100000/128)
#define BCAP 4608            // slots per bucket region (mean 4092 + 8 sigma)
#define AGG_ROWS 128

typedef __attribute__((ext_vector_type(8))) short bf16x8;
typedef __attribute__((ext_vector_type(4))) float f32x4;

// round-to-nearest-even fp32 -> bf16 bits
__device__ __forceinline__ unsigned rne_bf16(float v) {
    unsigned u = __float_as_uint(v);
    return (u + 0x7FFFu + ((u >> 16) & 1u)) >> 16;
}

// ---------------------------------------------------------------------------
// K1: init per-bucket global cursors (padded to one 64B line each)
// ---------------------------------------------------------------------------
__global__ void init_cursors_kernel(int* __restrict__ gcursor) {
    int i = blockIdx.x * blockDim.x + threadIdx.x;
    if (i < NBUCK) gcursor[i << 4] = i * BCAP;
}

// ---------------------------------------------------------------------------
// K2 (fat): blocks [0,782) = GEMM y16 = packed-bf16(x@W^T);
//           blocks [782,1173) = multisplit of 8192 edges into 782 buckets.
// ---------------------------------------------------------------------------
struct SplitSh {
    unsigned short srt[SPLIT_T];   // locally bucket-sorted edge indices
    int hist[NBUCK];
    int start[NBUCK + 2];
    int gbase[NBUCK];
    int cur[NBUCK];
    int scan[512];
};
union FatSh {
    unsigned short wlds[16384];    // 32 KB: W in B-fragment order (GEMM path)
    SplitSh sp;                    // 30,952 B (split path)
};

__global__ void __launch_bounds__(512, 4)
fat_gemm_split_kernel(const float* __restrict__ x, const float* __restrict__ W,
                      unsigned* __restrict__ y16u,
                      const int* __restrict__ rows, const int* __restrict__ cols,
                      const float* __restrict__ vals,
                      int* __restrict__ gcursor, int2* __restrict__ bins) {
    __shared__ FatSh sh;
    int tid = threadIdx.x;

    if (blockIdx.x >= GEMM_BLOCKS) {
        // ================= multisplit path =================
        SplitSh& S = sh.sp;
        int b  = blockIdx.x - GEMM_BLOCKS;
        int g0 = b * SPLIT_T;
        int cnt = min(SPLIT_T, N_EDGES - g0);

        for (int i = tid; i < NBUCK; i += 512) S.hist[i] = 0;
        __syncthreads();

        // local histogram over buckets (row >> 7)
        for (int j = tid; j < cnt; j += 512)
            atomicAdd(&S.hist[rows[g0 + j] >> 7], 1);
        __syncthreads();

        // exclusive scan of 782 via pair-sum + 512-wide Hillis-Steele
        int pairsum = (tid < 391) ? (S.hist[2 * tid] + S.hist[2 * tid + 1]) : 0;
        S.scan[tid] = pairsum;
        __syncthreads();
        for (int off = 1; off < 512; off <<= 1) {
            int v = (tid >= off) ? S.scan[tid - off] : 0;
            __syncthreads();
            S.scan[tid] += v;
            __syncthreads();
        }
        if (tid < 391) {
            int e = (tid == 0) ? 0 : S.scan[tid - 1];
            S.start[2 * tid]     = e;
            S.start[2 * tid + 1] = e + S.hist[2 * tid];
            S.cur[2 * tid]       = S.start[2 * tid];
            S.cur[2 * tid + 1]   = S.start[2 * tid + 1];
        }
        if (tid == 0) S.start[NBUCK] = cnt;
        __syncthreads();

        // reserve contiguous global space per bucket; local counting sort
        for (int i = tid; i < NBUCK; i += 512)
            S.gbase[i] = atomicAdd(&gcursor[i << 4], S.hist[i]);
        for (int j = tid; j < cnt; j += 512) {
            int pos = atomicAdd(&S.cur[rows[g0 + j] >> 7], 1);
            S.srt[pos] = (unsigned short)j;
        }
        __syncthreads();

        // write bucket runs to global, coalesced along idx
        for (int idx = tid; idx < cnt; idx += 512) {
            int lo = 0, hi = NBUCK - 1;           // max b with start[b] <= idx
            while (lo < hi) {
                int mid = (lo + hi + 1) >> 1;
                if (S.start[mid] <= idx) lo = mid; else hi = mid - 1;
            }
            int s = S.srt[idx];
            int r = rows[g0 + s];
            int2 rec;
            rec.x = cols[g0 + s] | ((r & 127) << 20);
            rec.y = __float_as_int(vals[g0 + s]);
            bins[S.gbase[lo] + (idx - S.start[lo])] = rec;
        }
        return;
    }

    // ================= gemm path =================
    // stage W: 4096 float4s over 512 threads, swizzled to B-fragment order
#pragma unroll
    for (int it = 0; it < 8; ++it) {
        int idx4 = tid + it * 512;
        int n    = idx4 >> 5;                // W row (output feature)
        int k4   = idx4 & 31;
        float4 v = ((const float4*)W)[idx4];
        int k0    = k4 * 4;
        int chunk = k0 >> 5;
        int quadw = (k0 >> 3) & 3;
        int j0    = k0 & 7;
        int lanef = quadw * 16 + (n & 15);
        int ntile = n >> 4;
        int base  = ((ntile * 4 + chunk) * 64 + lanef) * 8 + j0;
        float vv[4] = {v.x, v.y, v.z, v.w};
#pragma unroll
        for (int e = 0; e < 4; ++e)
            sh.wlds[base + e] = (unsigned short)rne_bf16(vv[e]);
    }
    __syncthreads();

    int wave = tid >> 6, lane = tid & 63;
    int quad = lane >> 4, l16 = lane & 15;
    int nodeBase = blockIdx.x * 128 + wave * 16;
    if (nodeBase >= N_NODES) return;         // exact: 100000 = 6250 * 16

    bf16x8 a_hi[4];
    const float* xrow = x + (size_t)(nodeBase + l16) * F + quad * 8;
#pragma unroll
    for (int c = 0; c < 4; ++c) {
        float4 p0 = *(const float4*)(xrow + c * 32);
        float4 p1 = *(const float4*)(xrow + c * 32 + 4);
        float vv[8] = {p0.x, p0.y, p0.z, p0.w, p1.x, p1.y, p1.z, p1.w};
#pragma unroll
        for (int j = 0; j < 8; ++j) a_hi[c][j] = (short)rne_bf16(vv[j]);
    }

    // features paired (f, f+64) in one uint: tile nt and nt+4 together
#pragma unroll 1
    for (int nt = 0; nt < 4; ++nt) {
        f32x4 alo = {0.f, 0.f, 0.f, 0.f};
        f32x4 ahi = {0.f, 0.f, 0.f, 0.f};
#pragma unroll
        for (int c = 0; c < 4; ++c) {
            bf16x8 blo = *(const bf16x8*)&sh.wlds[(((nt    ) * 4 + c) * 64 + lane) * 8];
            bf16x8 bhi = *(const bf16x8*)&sh.wlds[(((nt + 4) * 4 + c) * 64 + lane) * 8];
            alo = __builtin_amdgcn_mfma_f32_16x16x32_bf16(a_hi[c], blo, alo, 0, 0, 0);
            ahi = __builtin_amdgcn_mfma_f32_16x16x32_bf16(a_hi[c], bhi, ahi, 0, 0, 0);
        }
#pragma unroll
        for (int r = 0; r < 4; ++r) {
            unsigned lo = rne_bf16(alo[r]);
            unsigned hi = rne_bf16(ahi[r]);
            y16u[(size_t)(nodeBase + quad * 4 + r) * 64 + nt * 16 + l16] =
                lo | (hi << 16);
        }
    }
}

// ---------------------------------------------------------------------------
// K3: bucket aggregate. One block per 128-row bucket; 64 KB LDS fp32
// accumulators (bias-initialized); ds_add_f32, no global atomics.
// lane l owns features l and l+64 (matches y16 packing).
// ---------------------------------------------------------------------------
__global__ void __launch_bounds__(512, 2)
bucket_aggregate_kernel(const int* __restrict__ gcursor, const int2* __restrict__ bins,
                        const unsigned* __restrict__ y16u,
                        const float* __restrict__ bias, float* __restrict__ out) {
    __shared__ float acc[AGG_ROWS * F];      // 64 KB
    int tid = threadIdx.x;
    int b   = blockIdx.x;

    {   // init with bias: i & 31 == tid & 31 is loop-invariant
        float4 bv = ((const float4*)bias)[tid & 31];
        float4* a4 = (float4*)acc;
        for (int i = tid; i < AGG_ROWS * 32; i += 512) a4[i] = bv;
    }
    __syncthreads();

    int base = b * BCAP;
    int cnt  = gcursor[b << 4] - base;
    int lane = tid & 63;
    int wave = tid >> 6;

    for (int c0 = wave * 64; c0 < cnt; c0 += 512) {
        int have = min(64, cnt - c0);
        int2 rec = make_int2(0, 0);
        if (lane < have) rec = bins[base + c0 + lane];

        if (have == 64) {
#pragma unroll 4
            for (int j = 0; j < 64; ++j) {
                int meta = __shfl(rec.x, j);
                float v  = __int_as_float(__shfl(rec.y, j));
                int col  = meta & 0xFFFFF;
                int rl   = (meta >> 20) & 127;
                unsigned u = y16u[(size_t)col * 64 + lane];
                atomicAdd(&acc[rl * F + lane],      v * __uint_as_float(u << 16));
                atomicAdd(&acc[rl * F + 64 + lane], v * __uint_as_float(u & 0xFFFF0000u));
            }
        } else {
            for (int j = 0; j < have; ++j) {
                int meta = __shfl(rec.x, j);
                float v  = __int_as_float(__shfl(rec.y, j));
                int col  = meta & 0xFFFFF;
                int rl   = (meta >> 20) & 127;
                unsigned u = y16u[(size_t)col * 64 + lane];
                atomicAdd(&acc[rl * F + lane],      v * __uint_as_float(u << 16));
                atomicAdd(&acc[rl * F + 64 + lane], v * __uint_as_float(u & 0xFFFF0000u));
            }
        }
    }
    __syncthreads();

    // write out 128 rows x 128 feats, coalesced (features in natural order)
    float4* a4 = (float4*)acc;
    for (int i = tid; i < AGG_ROWS * 32; i += 512) {
        int gr = b * AGG_ROWS + (i >> 5);
        if (gr < N_NODES)
            ((float4*)out)[(size_t)gr * 32 + (i & 31)] = a4[i];
    }
}

// ---------------------------------------------------------------------------
// Fallback (ws too small): bias-init + atomic scatter from packed y16
// ---------------------------------------------------------------------------
__global__ void init_out_kernel(float* __restrict__ out, const float* __restrict__ b) {
    int idx = blockIdx.x * blockDim.x + threadIdx.x;
    const int total4 = N_NODES * F / 4;
    if (idx < total4) {
        int o4 = idx & (F / 4 - 1);
        ((float4*)out)[idx] = ((const float4*)b)[o4];
    }
}

__global__ void __launch_bounds__(256)
scatter_edges_bf16_kernel(const int* __restrict__ rows, const int* __restrict__ cols,
                          const float* __restrict__ vals,
                          const unsigned* __restrict__ y16u, float* __restrict__ out) {
    long long t = (long long)blockIdx.x * blockDim.x + threadIdx.x;
    int e = (int)(t >> 6);
    int lane = (int)(t & 63);
    if (e >= N_EDGES) return;
    int r = rows[e];
    int c = cols[e];
    float v = vals[e];
    unsigned u = y16u[(size_t)c * 64 + lane];
    float* o = out + (size_t)r * F;
    __hip_atomic_fetch_add(o + lane,      v * __uint_as_float(u << 16),
                           __ATOMIC_RELAXED, __HIP_MEMORY_SCOPE_AGENT);
    __hip_atomic_fetch_add(o + lane + 64, v * __uint_as_float(u & 0xFFFF0000u),
                           __ATOMIC_RELAXED, __HIP_MEMORY_SCOPE_AGENT);
}

// ---------------------------------------------------------------------------
extern "C" void kernel_launch(void* const* d_in, const int* in_sizes, int n_in,
                              void* d_out, int out_size, void* d_ws, size_t ws_size,
                              hipStream_t stream) {
    const int*   L_rows = (const int*)d_in[0];
    const int*   L_cols = (const int*)d_in[1];
    const float* L_vals = (const float*)d_in[2];
    const float* x      = (const float*)d_in[3];
    const float* W      = (const float*)d_in[4];
    const float* b      = (const float*)d_in[5];
    float* out = (float*)d_out;

    // Workspace layout (bytes):
    //   y16     @ 0          : N*F*2              = 25,600,000
    //   gcursor @ 25,600,000 : NBUCK * 64B        =     50,048
    //   bins    @ 25,650,048 : NBUCK * BCAP * 8   = 28,827,648
    const size_t OFF_CURS = 25600000;
    const size_t OFF_BINS = 25650048;
    const size_t WS_NEEDED = 54477696;

    char* ws = (char*)d_ws;
    unsigned* y16u = (unsigned*)ws;

    if (ws_size >= WS_NEEDED) {
        int*  gcursor = (int*)(ws + OFF_CURS);
        int2* bins    = (int2*)(ws + OFF_BINS);

        hipLaunchKernelGGL(init_cursors_kernel, dim3(2), dim3(512), 0, stream, gcursor);
        hipLaunchKernelGGL(fat_gemm_split_kernel, dim3(GEMM_BLOCKS + SPLIT_BLOCKS),
                           dim3(512), 0, stream,
                           x, W, y16u, L_rows, L_cols, L_vals, gcursor, bins);
        hipLaunchKernelGGL(bucket_aggregate_kernel, dim3(NBUCK), dim3(512), 0, stream,
                           gcursor, bins, y16u, b, out);
    } else {
        int total4 = N_NODES * F / 4;
        hipLaunchKernelGGL(init_out_kernel, dim3((total4 + 255) / 256), dim3(256), 0,
                           stream, out, b);
        hipLaunchKernelGGL(fat_gemm_split_kernel, dim3(GEMM_BLOCKS), dim3(512), 0,
                           stream, x, W, y16u, L_rows, L_cols, L_vals,
                           (int*)nullptr, (int2*)nullptr);
        long long threads = (long long)N_EDGES * 64;
        hipLaunchKernelGGL(scatter_edges_bf16_kernel,
                           dim3((int)((threads + 255) / 256)), dim3(256), 0, stream,
                           L_rows, L_cols, L_vals, y16u, out);
    }
}